// Round 19
// baseline (485.857 us; speedup 1.0000x reference)
//
#include <hip/hip_runtime.h>

// Soft-DTW (gamma=1), batched 64 x (1024 vs 1024, 2-D points).
//
// === R19: R17 champion + PRODUCER-asm pins (kill rematerialization) ===
// R18 closed the cross-block question: every multi-block-per-batch variant
// (R10/11/13/14/18) loses to LDS-only -- the global handoff RT sits on the
// inter-wave critical path every epoch. Champion structure stands: one
// block per batch, 64 blocks x 512 thr, 8 waves (2/SIMD), 2 rows/lane.
//
// R17's null pin result + VGPR=56 + zero scratch => the compiler
// REMATERIALIZES the prefetched arrays at their uses: per chain step it
// re-does contour-load + sqdist + exp2 (k2) and ds_read + 2 f64 mul (vr)
// ON the serial chain. Input-only asm pins can't stop this (pure values
// can be duplicated: one copy for the pin, a fresh one sunk to the use).
// Fix: route each prefetched value THROUGH asm volatile v_mov_b32 with an
// output constraint -- the asm becomes the value's producer, which LLVM
// can neither duplicate nor move; consumers must read its output register.
// Confirming signal: VGPR_Count must jump 56 -> >=120.
//
// Geometry (R15-R17): lane owns rows 2l (lo) and 2l+1 (hi); hi cell's
// predecessors are this lane's own cur_lo/old_lo (no DPP); lo+hi cells
// independent per step (2x ILP); contour reuse c_h(k) = c_l(k-1); LDS
// parity ring between waves; one __syncthreads per epoch.
//
// Core (verified absmax 0.0 since R8): exp2-domain Z = 2^(off - R*log2e);
//   Z_d[i] = 2^(-D*log2e) * (Zdiag + Zup + Zleft)
// Per-cell op order bit-identical: zn = k2 * ((nb2 + nb1) + cur); zero
// transcendentals on-chain; per-wave exact power-of-2 rescale per epoch
// (DPP max-reduce, pure VALU); lane-0 neighbor values converted by exact
// 2^(off-oin) two-stage factors; ring parity double-buffer (reader epoch g
// reads writer epoch g-1, parity (g^1)&1; overwrite 2 barriers later).
// Inactive cells: k2=0 -> zn=0. Final cell (row 1023, d=2046) snapshotted
// at its own step (exact); R = (res_off - log2(res)) * ln2.

#define N 1024
#define TPB 512
#define WPB 8                                  // waves per block = per batch
#define K 16                                   // diagonals per epoch
#define NGRP ((128 * (WPB - 1) + 1148) / K + (WPB - 1) + 1)   // 135
#define L2E 1.442695040888963f
#define LN2D 0.6931471805599453

__device__ __forceinline__ float sqdist2(float2 a, float2 b) {
    float dx = a.x - b.x;
    float dy = a.y - b.y;
    return dx * dx + dy * dy;
}

// PRODUCER pins: the asm is the value's producer (volatile, has an output)
// -> cannot be rematerialized/duplicated/sunk. Bit-exact (plain mov).
__device__ __forceinline__ float pin_f(float x) {
    float y;
    asm volatile("v_mov_b32 %0, %1" : "=v"(y) : "v"(x));
    return y;
}
__device__ __forceinline__ double pin_d(double x) {
    long long v = __double_as_longlong(x);
    int lo = (int)(v & 0xffffffffLL), hi = (int)(v >> 32);
    asm volatile("v_mov_b32 %0, %1" : "=v"(lo) : "v"(lo));
    asm volatile("v_mov_b32 %0, %1" : "=v"(hi) : "v"(hi));
    return __longlong_as_double(((long long)hi << 32) | (unsigned int)lo);
}

// 64-bit DPP move (two 32-bit halves, same lane pattern; invalid lanes -> 0).
template <int CTRL>
__device__ __forceinline__ double dpp_movd(double src) {
    long long s = __double_as_longlong(src);
    int lo = __builtin_amdgcn_update_dpp(0, (int)(s & 0xffffffffLL),
                                         CTRL, 0xF, 0xF, false);
    int hi = __builtin_amdgcn_update_dpp(0, (int)(s >> 32),
                                         CTRL, 0xF, 0xF, false);
    return __longlong_as_double(((long long)hi << 32) | (unsigned int)lo);
}

template <int CTRL>
__device__ __forceinline__ int dpp_maxstep(int x) {
    int s = __builtin_amdgcn_update_dpp(0, x, CTRL, 0xF, 0xF, false);
    return max(x, s);
}

// Full 64-lane max of a nonneg int, pure VALU (no LDS); result wave-uniform.
__device__ __forceinline__ int wave_max_i(int x) {
    x = dpp_maxstep<0x111>(x);   // row_shr:1
    x = dpp_maxstep<0x112>(x);   // row_shr:2
    x = dpp_maxstep<0x114>(x);   // row_shr:4
    x = dpp_maxstep<0x118>(x);   // row_shr:8
    x = dpp_maxstep<0x142>(x);   // row_bcast15
    x = dpp_maxstep<0x143>(x);   // row_bcast31
    return __builtin_amdgcn_readlane(x, 63);
}

// exact 2^s as double for s in [-1022, 1023]
__device__ __forceinline__ double pow2d(int s) {
    return __longlong_as_double((long long)(1023 + s) << 52);
}

__global__ __launch_bounds__(TPB, 2) void dtw_kernel(
    const float2* __restrict__ snake,
    const float2* __restrict__ contour,
    float* __restrict__ out)
{
    const int t    = threadIdx.x;
    const int lane = t & 63;
    const int w    = t >> 6;                 // wave 0..7
    const int b    = blockIdx.x;             // batch
    const int il   = (w << 7) + 2 * lane;    // lo row
    const int ih   = il + 1;                 // hi row

    __shared__ double ringv[WPB][2][K];      // boundary ring (LDS only)
    __shared__ int    ringo[WPB][2];
    __shared__ float  initvals[3];           // R0[0], R1[0], R1[1]

    const float2* sg = snake   + (size_t)b * N;
    const float2* cg = contour + (size_t)b * N;
    const float2 sp_l = sg[il];              // snake points: registers
    const float2 sp_h = sg[ih];

    if (t < WPB * 2 * K) ((double*)ringv)[t] = 0.0;   // Z(INF) = 0
    if (t < WPB * 2)     ((int*)ringo)[t] = 0;
    if (t == 0) {
        // Diagonals 0 and 1 (reference `init`):
        float2 s0 = sg[0], s1 = sg[1], c0 = cg[0], c1 = cg[1];
        float d00 = sqdist2(s0, c0);
        initvals[0] = d00;
        initvals[1] = sqdist2(s0, c1) + d00;
        initvals[2] = sqdist2(s1, c0) + d00;
    }
    __syncthreads();

    // State entering d=2 (off = 0):
    //   cur_lo = Z_{d-1}[il], cur_hi = Z_{d-1}[ih], old_lo = Z_{d-2}[il],
    //   nbh1 = Z_{d-1}[il-1], nbh2 = Z_{d-2}[il-1]  (neighbor lane's hi row)
    double cur_lo = 0.0, cur_hi = 0.0, old_lo = 0.0;
    double nbh1 = 0.0, nbh2 = 0.0;
    int off = 0;
    bool adopted = (w == 0);
    if (t == 0) {            // rows 0,1: R1[0], R1[1], R0[0]
        cur_lo = (double)__builtin_amdgcn_exp2f(-L2E * initvals[1]);
        cur_hi = (double)__builtin_amdgcn_exp2f(-L2E * initvals[2]);
        old_lo = (double)__builtin_amdgcn_exp2f(-L2E * initvals[0]);
    } else if (t == 1) {     // row 2's left neighbor = row 1 at d=1
        nbh1 = (double)__builtin_amdgcn_exp2f(-L2E * initvals[2]);
    }

    double res = 1.0;                        // final-cell snapshot
    int res_off = 0;

    const int lo = (w == 0) ? 2 : (128 * w - 1);  // -1 pre-step seeds nbh1
    const int hi = 128 * w + 127 + (N - 1);       // 128w + 1150
    int d0 = 2 - K * w;

    float k2l[K], k2h[K];                    // step factors, f32 (pinned)
    double vr[K];                            // converted ring (lane 0 only)
    #pragma unroll
    for (int k = 0; k < K; ++k) vr[k] = 0.0;

    // Epoch-0 factors (pinned). Contour reuse: c_h(k) = c_l(k-1).
    {
        float2 cprev = cg[(unsigned)(d0 - 1 - il) & (N - 1)];
        #pragma unroll
        for (int k = 0; k < K; ++k) {
            const unsigned ul = (unsigned)(d0 + k - il);
            const unsigned uh = (unsigned)(d0 + k - ih);
            float2 cc = cg[ul & (N - 1)];
            float el = __builtin_amdgcn_exp2f(sqdist2(sp_l, cc) * (-L2E));
            float eh = __builtin_amdgcn_exp2f(sqdist2(sp_h, cprev) * (-L2E));
            k2l[k] = pin_f((ul < (unsigned)N) ? el : 0.0f);
            k2h[k] = pin_f((uh < (unsigned)N) ? eh : 0.0f);
            cprev = cc;
        }
    }

    for (int g = 0; g < NGRP; ++g) {
        const bool overlap = (d0 <= hi) && (d0 + (K - 1) >= lo);
        if (overlap) {
            if (w > 0) {
                const int p = (g ^ 1) & 1;
                int oin = ringo[w - 1][p];            // LDS broadcast
                if (!adopted) { off = oin; adopted = true; }
                if (lane == 0) {
                    int dl = off - oin;
                    int c1 = min(max(dl, -1022), 1022);
                    int c2 = min(max(dl - c1, -1022), 1022);
                    double f1 = pow2d(c1), f2 = pow2d(c2);
                    const double* q = &ringv[w - 1][p][0];
                    #pragma unroll
                    for (int k = 0; k < K; ++k)
                        vr[k] = pin_d((q[k] * f1) * f2);   // producer pin
                }
            }

            const int kres = (ih + N - 1) - d0;  // step of hi row's last cell
            const bool pub = (lane == 63) && (w < WPB - 1);

            // Chain: two INDEPENDENT cells per step (hi uses pre-update lo).
            // Pure f64+DPP now -- prefetched k2/vr arrive from registers.
            #pragma unroll
            for (int k = 0; k < K; ++k) {
                double zn_h = (double)k2h[k] * ((old_lo + cur_lo) + cur_hi);
                double zn_l = (double)k2l[k] * ((nbh2 + nbh1) + cur_lo);
                if (k == kres) { res = zn_h; res_off = off; }
                if (pub) ringv[w][g & 1][k] = zn_h;   // off-chain LDS store
                old_lo = cur_lo;
                cur_lo = zn_l;
                cur_hi = zn_h;
                double a  = dpp_movd<0x111>(zn_h);   // row_shr:1
                double bc = dpp_movd<0x142>(zn_h);   // row_bcast15
                double up = ((lane & 15) == 0) ? bc : a;
                nbh2 = nbh1;
                nbh1 = (lane == 0) ? vr[k] : up;
            }

            if (pub) ringo[w][g & 1] = off;          // pre-rescale offset

            // Per-wave exact power-of-2 rescale (DPP max-reduce, no LDS).
            int el = (int)((__double_as_longlong(cur_lo) >> 52) & 0x7FF);
            int eh = (int)((__double_as_longlong(cur_hi) >> 52) & 0x7FF);
            int e = wave_max_i(max(el, eh));
            if (e > 0) {
                int sh = 1023 - e;
                int c1 = min(max(sh, -1022), 1022);
                int c2 = min(max(sh - c1, -1022), 1022);
                double f1 = pow2d(c1), f2 = pow2d(c2);
                cur_lo = (cur_lo * f1) * f2;
                cur_hi = (cur_hi * f1) * f2;
                old_lo = (old_lo * f1) * f2;
                nbh1   = (nbh1   * f1) * f2;
                nbh2   = (nbh2   * f1) * f2;
                off += sh;
            }
        }

        d0 += K;

        // Epoch bottom: next-epoch factors, PINNED (true prefetch -- the
        // producer asm cannot be sunk past the barrier or into the chain).
        {
            float2 cprev = cg[(unsigned)(d0 - 1 - il) & (N - 1)];
            #pragma unroll
            for (int k = 0; k < K; ++k) {
                const unsigned ul = (unsigned)(d0 + k - il);
                const unsigned uh = (unsigned)(d0 + k - ih);
                float2 cc = cg[ul & (N - 1)];
                float el2 = __builtin_amdgcn_exp2f(sqdist2(sp_l, cc) * (-L2E));
                float eh2 = __builtin_amdgcn_exp2f(sqdist2(sp_h, cprev) * (-L2E));
                k2l[k] = pin_f((ul < (unsigned)N) ? el2 : 0.0f);
                k2h[k] = pin_f((uh < (unsigned)N) ? eh2 : 0.0f);
                cprev = cc;
            }
        }

        __syncthreads();
    }

    // Row 1023 = hi row of wave 7, lane 63 (t = 511): res = Z of
    // R[1023,1023] at res_off (exact snapshot; rescales are powers of 2).
    if (t == TPB - 1) {
        double R = ((double)res_off - log2(res)) * LN2D;
        atomicAdd(out, (float)(R * (1.0 / 64.0)));
    }
}

extern "C" void kernel_launch(void* const* d_in, const int* in_sizes, int n_in,
                              void* d_out, int out_size, void* d_ws, size_t ws_size,
                              hipStream_t stream) {
    const float2* snake   = (const float2*)d_in[0];
    const float2* contour = (const float2*)d_in[1];
    float* out = (float*)d_out;
    // Harness re-poisons d_out to 0xAA before every timed launch.
    hipMemsetAsync(out, 0, sizeof(float), stream);
    dtw_kernel<<<64, TPB, 0, stream>>>(snake, contour, out);
}

// Round 20
// 408.596 us; speedup vs baseline: 1.1891x; 1.1891x over previous
//
#include <hip/hip_runtime.h>

// Soft-DTW (gamma=1), batched 64 x (1024 vs 1024, 2-D points).
//
// === R20: R17 champion, ONE change: K=16 -> 32 (halve per-epoch overhead) ===
// R19 closed the pin/remat axis: producer-asm pins serialized (315->437)
// and input pins were neutral (R17=315 ~ R16=319). Champion structure:
// one block per batch, 64 blocks x 512 thr, 8 waves (2 waves/SIMD),
// 2 rows/lane, LDS-only transport (every cross-block variant lost).
// R17 decomposition: 5610 cyc/epoch x 135 epochs, active-CU VALU ~71%.
// Remaining lever: per-epoch FIXED costs (barrier convoy, rescale =
// 6-DPP-reduce + 10 f64 muls, lane-0 ring conversion) paid 135x.
// K=32 halves epoch count (135 -> 71) with unchanged per-step math.
// (R14's K=32 test was confounded by the PARTS=4 global-handoff geometry;
// this is the clean test on the LDS-only champion.) Rescale interval
// doubles: 32 steps x ~13 bits + spread << fp64's 2046-bit window ->
// exactness preserved, absmax 0.0 expected.
//
// Geometry (R15-R17): lane owns rows 2l (lo) and 2l+1 (hi); hi cell's
// predecessors are this lane's own cur_lo/old_lo (no DPP); lo+hi cells
// independent per step (2x ILP); contour reuse c_h(k) = c_l(k-1); LDS
// parity ring between waves; one __syncthreads per epoch.
//
// Core (verified absmax 0.0 since R8): exp2-domain Z = 2^(off - R*log2e);
//   Z_d[i] = 2^(-D*log2e) * (Zdiag + Zup + Zleft)
// Per-cell op order bit-identical: zn = k2 * ((nb2 + nb1) + cur); zero
// transcendentals on-chain; per-wave exact power-of-2 rescale per epoch
// (DPP max-reduce, pure VALU); lane-0 neighbor values converted by exact
// 2^(off-oin) two-stage factors; ring parity double-buffer (reader epoch g
// reads writer epoch g-1, parity (g^1)&1; overwrite 2 barriers later).
// Inactive cells: k2=0 -> zn=0. Final cell (row 1023, d=2046) snapshotted
// at its own step (exact); R = (res_off - log2(res)) * ln2.

#define N 1024
#define TPB 512
#define WPB 8                                  // waves per block = per batch
#define K 32                                   // diagonals per epoch
#define NGRP ((128 * (WPB - 1) + 1148) / K + (WPB - 1) + 1)   // 71
#define L2E 1.442695040888963f
#define LN2D 0.6931471805599453

#define PIN_D(x) asm volatile("" :: "v"(x))
#define PIN_F(x) asm volatile("" :: "v"(x))

__device__ __forceinline__ float sqdist2(float2 a, float2 b) {
    float dx = a.x - b.x;
    float dy = a.y - b.y;
    return dx * dx + dy * dy;
}

// 64-bit DPP move (two 32-bit halves, same lane pattern; invalid lanes -> 0).
template <int CTRL>
__device__ __forceinline__ double dpp_movd(double src) {
    long long s = __double_as_longlong(src);
    int lo = __builtin_amdgcn_update_dpp(0, (int)(s & 0xffffffffLL),
                                         CTRL, 0xF, 0xF, false);
    int hi = __builtin_amdgcn_update_dpp(0, (int)(s >> 32),
                                         CTRL, 0xF, 0xF, false);
    return __longlong_as_double(((long long)hi << 32) | (unsigned int)lo);
}

template <int CTRL>
__device__ __forceinline__ int dpp_maxstep(int x) {
    int s = __builtin_amdgcn_update_dpp(0, x, CTRL, 0xF, 0xF, false);
    return max(x, s);
}

// Full 64-lane max of a nonneg int, pure VALU (no LDS); result wave-uniform.
__device__ __forceinline__ int wave_max_i(int x) {
    x = dpp_maxstep<0x111>(x);   // row_shr:1
    x = dpp_maxstep<0x112>(x);   // row_shr:2
    x = dpp_maxstep<0x114>(x);   // row_shr:4
    x = dpp_maxstep<0x118>(x);   // row_shr:8
    x = dpp_maxstep<0x142>(x);   // row_bcast15
    x = dpp_maxstep<0x143>(x);   // row_bcast31
    return __builtin_amdgcn_readlane(x, 63);
}

// exact 2^s as double for s in [-1022, 1023]
__device__ __forceinline__ double pow2d(int s) {
    return __longlong_as_double((long long)(1023 + s) << 52);
}

__global__ __launch_bounds__(TPB, 2) void dtw_kernel(
    const float2* __restrict__ snake,
    const float2* __restrict__ contour,
    float* __restrict__ out)
{
    const int t    = threadIdx.x;
    const int lane = t & 63;
    const int w    = t >> 6;                 // wave 0..7
    const int b    = blockIdx.x;             // batch
    const int il   = (w << 7) + 2 * lane;    // lo row
    const int ih   = il + 1;                 // hi row

    __shared__ double ringv[WPB][2][K];      // boundary ring (LDS only)
    __shared__ int    ringo[WPB][2];
    __shared__ float  initvals[3];           // R0[0], R1[0], R1[1]

    const float2* sg = snake   + (size_t)b * N;
    const float2* cg = contour + (size_t)b * N;
    const float2 sp_l = sg[il];              // snake points: registers
    const float2 sp_h = sg[ih];

    if (t < WPB * 2 * K) ((double*)ringv)[t] = 0.0;   // Z(INF) = 0 (512 slots)
    if (t < WPB * 2)     ((int*)ringo)[t] = 0;
    if (t == 0) {
        // Diagonals 0 and 1 (reference `init`):
        float2 s0 = sg[0], s1 = sg[1], c0 = cg[0], c1 = cg[1];
        float d00 = sqdist2(s0, c0);
        initvals[0] = d00;
        initvals[1] = sqdist2(s0, c1) + d00;
        initvals[2] = sqdist2(s1, c0) + d00;
    }
    __syncthreads();

    // State entering d=2 (off = 0):
    //   cur_lo = Z_{d-1}[il], cur_hi = Z_{d-1}[ih], old_lo = Z_{d-2}[il],
    //   nbh1 = Z_{d-1}[il-1], nbh2 = Z_{d-2}[il-1]  (neighbor lane's hi row)
    double cur_lo = 0.0, cur_hi = 0.0, old_lo = 0.0;
    double nbh1 = 0.0, nbh2 = 0.0;
    int off = 0;
    bool adopted = (w == 0);
    if (t == 0) {            // rows 0,1: R1[0], R1[1], R0[0]
        cur_lo = (double)__builtin_amdgcn_exp2f(-L2E * initvals[1]);
        cur_hi = (double)__builtin_amdgcn_exp2f(-L2E * initvals[2]);
        old_lo = (double)__builtin_amdgcn_exp2f(-L2E * initvals[0]);
    } else if (t == 1) {     // row 2's left neighbor = row 1 at d=1
        nbh1 = (double)__builtin_amdgcn_exp2f(-L2E * initvals[2]);
    }

    double res = 1.0;                        // final-cell snapshot
    int res_off = 0;

    const int lo = (w == 0) ? 2 : (128 * w - 1);  // -1 pre-step seeds nbh1
    const int hi = 128 * w + 127 + (N - 1);       // 128w + 1150
    int d0 = 2 - K * w;

    float k2l[K], k2h[K];                    // step factors, f32
    double vr[K];                            // converted ring (lane 0 only)
    #pragma unroll
    for (int k = 0; k < K; ++k) vr[k] = 0.0;

    // Epoch-0 factors. Contour reuse: c_h(k) = c_l(k-1).
    {
        float2 cprev = cg[(unsigned)(d0 - 1 - il) & (N - 1)];
        #pragma unroll
        for (int k = 0; k < K; ++k) {
            const unsigned ul = (unsigned)(d0 + k - il);
            const unsigned uh = (unsigned)(d0 + k - ih);
            float2 cc = cg[ul & (N - 1)];
            float el = __builtin_amdgcn_exp2f(sqdist2(sp_l, cc) * (-L2E));
            float eh = __builtin_amdgcn_exp2f(sqdist2(sp_h, cprev) * (-L2E));
            k2l[k] = (ul < (unsigned)N) ? el : 0.0f;
            k2h[k] = (uh < (unsigned)N) ? eh : 0.0f;
            cprev = cc;
        }
    }

    for (int g = 0; g < NGRP; ++g) {
        const bool overlap = (d0 <= hi) && (d0 + (K - 1) >= lo);
        if (overlap) {
            if (w > 0) {
                const int p = (g ^ 1) & 1;
                int oin = ringo[w - 1][p];            // LDS broadcast
                if (!adopted) { off = oin; adopted = true; }
                if (lane == 0) {
                    int dl = off - oin;
                    int c1 = min(max(dl, -1022), 1022);
                    int c2 = min(max(dl - c1, -1022), 1022);
                    double f1 = pow2d(c1), f2 = pow2d(c2);
                    const double* q = &ringv[w - 1][p][0];
                    #pragma unroll
                    for (int k = 0; k < K; ++k)
                        vr[k] = (q[k] * f1) * f2;
                }
                // Input-only pins (neutral in R17; keep for parity).
                #pragma unroll
                for (int k = 0; k < K; ++k) PIN_D(vr[k]);
            }

            const int kres = (ih + N - 1) - d0;  // step of hi row's last cell
            const bool pub = (lane == 63) && (w < WPB - 1);

            // Chain: two INDEPENDENT cells per step (hi uses pre-update lo).
            // f32->f64 widening of k2 is exact (bit-identical).
            #pragma unroll
            for (int k = 0; k < K; ++k) {
                double zn_h = (double)k2h[k] * ((old_lo + cur_lo) + cur_hi);
                double zn_l = (double)k2l[k] * ((nbh2 + nbh1) + cur_lo);
                if (k == kres) { res = zn_h; res_off = off; }
                if (pub) ringv[w][g & 1][k] = zn_h;   // off-chain LDS store
                old_lo = cur_lo;
                cur_lo = zn_l;
                cur_hi = zn_h;
                double a  = dpp_movd<0x111>(zn_h);   // row_shr:1
                double bc = dpp_movd<0x142>(zn_h);   // row_bcast15
                double up = ((lane & 15) == 0) ? bc : a;
                nbh2 = nbh1;
                nbh1 = (lane == 0) ? vr[k] : up;
            }

            if (pub) ringo[w][g & 1] = off;          // pre-rescale offset

            // Per-wave exact power-of-2 rescale (DPP max-reduce, no LDS).
            int el = (int)((__double_as_longlong(cur_lo) >> 52) & 0x7FF);
            int eh = (int)((__double_as_longlong(cur_hi) >> 52) & 0x7FF);
            int e = wave_max_i(max(el, eh));
            if (e > 0) {
                int sh = 1023 - e;
                int c1 = min(max(sh, -1022), 1022);
                int c2 = min(max(sh - c1, -1022), 1022);
                double f1 = pow2d(c1), f2 = pow2d(c2);
                cur_lo = (cur_lo * f1) * f2;
                cur_hi = (cur_hi * f1) * f2;
                old_lo = (old_lo * f1) * f2;
                nbh1   = (nbh1   * f1) * f2;
                nbh2   = (nbh2   * f1) * f2;
                off += sh;
            }
        }

        d0 += K;

        // Epoch bottom: next-epoch factors.
        {
            float2 cprev = cg[(unsigned)(d0 - 1 - il) & (N - 1)];
            #pragma unroll
            for (int k = 0; k < K; ++k) {
                const unsigned ul = (unsigned)(d0 + k - il);
                const unsigned uh = (unsigned)(d0 + k - ih);
                float2 cc = cg[ul & (N - 1)];
                float el2 = __builtin_amdgcn_exp2f(sqdist2(sp_l, cc) * (-L2E));
                float eh2 = __builtin_amdgcn_exp2f(sqdist2(sp_h, cprev) * (-L2E));
                k2l[k] = (ul < (unsigned)N) ? el2 : 0.0f;
                k2h[k] = (uh < (unsigned)N) ? eh2 : 0.0f;
                cprev = cc;
            }
        }
        #pragma unroll
        for (int k = 0; k < K; ++k) { PIN_F(k2l[k]); PIN_F(k2h[k]); }

        __syncthreads();
    }

    // Row 1023 = hi row of wave 7, lane 63 (t = 511): res = Z of
    // R[1023,1023] at res_off (exact snapshot; rescales are powers of 2).
    if (t == TPB - 1) {
        double R = ((double)res_off - log2(res)) * LN2D;
        atomicAdd(out, (float)(R * (1.0 / 64.0)));
    }
}

extern "C" void kernel_launch(void* const* d_in, const int* in_sizes, int n_in,
                              void* d_out, int out_size, void* d_ws, size_t ws_size,
                              hipStream_t stream) {
    const float2* snake   = (const float2*)d_in[0];
    const float2* contour = (const float2*)d_in[1];
    float* out = (float*)d_out;
    // Harness re-poisons d_out to 0xAA before every timed launch.
    hipMemsetAsync(out, 0, sizeof(float), stream);
    dtw_kernel<<<64, TPB, 0, stream>>>(snake, contour, out);
}

// Round 21
// 364.304 us; speedup vs baseline: 1.3337x; 1.1216x over previous
//
#include <hip/hip_runtime.h>

// Soft-DTW (gamma=1), batched 64 x (1024 vs 1024, 2-D points).
//
// === R21 = R17 champion, FINAL (315.5 us, absmax 0.0) ===
// Session summary (534 -> 315.5 us, bit-exact at every step):
//  - exp2-domain recurrence: Z = 2^(off - R*log2e) turns softmin into
//    Z_d[i] = 2^(-D*log2e) * (Zdiag + Zup + Zleft) -- ZERO transcendentals
//    on the serial DP chain (the R0-R7 arc; fp64 + per-wave offset for the
//    ~400-bit within-wave dynamic range, R8).
//  - 2 rows/lane coarsening: hi cell's predecessors are the lane's own
//    registers; lo+hi independent per step (2x ILP); 8 waves/batch ->
//    one block per batch, 2 waves/SIMD (R15).
//  - slim register arrays (f32 k2, no wb[]) to avoid scratch (R16).
//  - LDS-only wave-skew pipeline, K=16/epoch, one barrier per epoch.
// Closed axes (all measured, all lost): cross-block CU-spread
// (R10/11/13/14/18 -- handoff RT on critical path), K=8/32 (R8/R14/R20),
// producer-asm pins (R19), >2 waves/SIMD (structurally impossible at 64
// batches). Final state: issue-bound on 64 active CUs (issue model 3700
// cyc/SIMD/epoch vs 5610 wall = 66% predicted, 71% measured VALU busy).
//
// Core correctness: per-cell op order zn = k2 * ((nb2 + nb1) + cur) with
// exact power-of-2 rescales (DPP max-reduce) and exact 2^(off-oin)
// conversions -> bit-identical to the f64 reference path; absmax 0.0
// verified on every passing round since R8. Ring parity double-buffer
// (reader epoch g reads writer epoch g-1, parity (g^1)&1; overwrite 2
// barriers later -> race-free). Inactive cells: k2=0 -> zn=0. Final cell
// (row 1023, d=2046) snapshotted at its own step; R = (res_off -
// log2(res)) * ln2; one atomicAdd per batch.

#define N 1024
#define TPB 512
#define WPB 8                                  // waves per block = per batch
#define K 16                                   // diagonals per epoch
#define NGRP ((128 * (WPB - 1) + 1148) / K + (WPB - 1) + 1)   // 135
#define L2E 1.442695040888963f
#define LN2D 0.6931471805599453

#define PIN_D(x) asm volatile("" :: "v"(x))
#define PIN_F(x) asm volatile("" :: "v"(x))

__device__ __forceinline__ float sqdist2(float2 a, float2 b) {
    float dx = a.x - b.x;
    float dy = a.y - b.y;
    return dx * dx + dy * dy;
}

// 64-bit DPP move (two 32-bit halves, same lane pattern; invalid lanes -> 0).
template <int CTRL>
__device__ __forceinline__ double dpp_movd(double src) {
    long long s = __double_as_longlong(src);
    int lo = __builtin_amdgcn_update_dpp(0, (int)(s & 0xffffffffLL),
                                         CTRL, 0xF, 0xF, false);
    int hi = __builtin_amdgcn_update_dpp(0, (int)(s >> 32),
                                         CTRL, 0xF, 0xF, false);
    return __longlong_as_double(((long long)hi << 32) | (unsigned int)lo);
}

template <int CTRL>
__device__ __forceinline__ int dpp_maxstep(int x) {
    int s = __builtin_amdgcn_update_dpp(0, x, CTRL, 0xF, 0xF, false);
    return max(x, s);
}

// Full 64-lane max of a nonneg int, pure VALU (no LDS); result wave-uniform.
__device__ __forceinline__ int wave_max_i(int x) {
    x = dpp_maxstep<0x111>(x);   // row_shr:1
    x = dpp_maxstep<0x112>(x);   // row_shr:2
    x = dpp_maxstep<0x114>(x);   // row_shr:4
    x = dpp_maxstep<0x118>(x);   // row_shr:8
    x = dpp_maxstep<0x142>(x);   // row_bcast15
    x = dpp_maxstep<0x143>(x);   // row_bcast31
    return __builtin_amdgcn_readlane(x, 63);
}

// exact 2^s as double for s in [-1022, 1023]
__device__ __forceinline__ double pow2d(int s) {
    return __longlong_as_double((long long)(1023 + s) << 52);
}

__global__ __launch_bounds__(TPB, 2) void dtw_kernel(
    const float2* __restrict__ snake,
    const float2* __restrict__ contour,
    float* __restrict__ out)
{
    const int t    = threadIdx.x;
    const int lane = t & 63;
    const int w    = t >> 6;                 // wave 0..7
    const int b    = blockIdx.x;             // batch
    const int il   = (w << 7) + 2 * lane;    // lo row
    const int ih   = il + 1;                 // hi row

    __shared__ double ringv[WPB][2][K];      // boundary ring (LDS only)
    __shared__ int    ringo[WPB][2];
    __shared__ float  initvals[3];           // R0[0], R1[0], R1[1]

    const float2* sg = snake   + (size_t)b * N;
    const float2* cg = contour + (size_t)b * N;
    const float2 sp_l = sg[il];              // snake points: registers
    const float2 sp_h = sg[ih];

    if (t < WPB * 2 * K) ((double*)ringv)[t] = 0.0;   // Z(INF) = 0
    if (t < WPB * 2)     ((int*)ringo)[t] = 0;
    if (t == 0) {
        // Diagonals 0 and 1 (reference `init`):
        float2 s0 = sg[0], s1 = sg[1], c0 = cg[0], c1 = cg[1];
        float d00 = sqdist2(s0, c0);
        initvals[0] = d00;
        initvals[1] = sqdist2(s0, c1) + d00;
        initvals[2] = sqdist2(s1, c0) + d00;
    }
    __syncthreads();

    // State entering d=2 (off = 0):
    //   cur_lo = Z_{d-1}[il], cur_hi = Z_{d-1}[ih], old_lo = Z_{d-2}[il],
    //   nbh1 = Z_{d-1}[il-1], nbh2 = Z_{d-2}[il-1]  (neighbor lane's hi row)
    double cur_lo = 0.0, cur_hi = 0.0, old_lo = 0.0;
    double nbh1 = 0.0, nbh2 = 0.0;
    int off = 0;
    bool adopted = (w == 0);
    if (t == 0) {            // rows 0,1: R1[0], R1[1], R0[0]
        cur_lo = (double)__builtin_amdgcn_exp2f(-L2E * initvals[1]);
        cur_hi = (double)__builtin_amdgcn_exp2f(-L2E * initvals[2]);
        old_lo = (double)__builtin_amdgcn_exp2f(-L2E * initvals[0]);
    } else if (t == 1) {     // row 2's left neighbor = row 1 at d=1
        nbh1 = (double)__builtin_amdgcn_exp2f(-L2E * initvals[2]);
    }

    double res = 1.0;                        // final-cell snapshot
    int res_off = 0;

    const int lo = (w == 0) ? 2 : (128 * w - 1);  // -1 pre-step seeds nbh1
    const int hi = 128 * w + 127 + (N - 1);       // 128w + 1150
    int d0 = 2 - K * w;

    float k2l[K], k2h[K];                    // step factors, f32
    double vr[K];                            // converted ring (lane 0 only)
    #pragma unroll
    for (int k = 0; k < K; ++k) vr[k] = 0.0;

    // Epoch-0 factors. Contour reuse: c_h(k) = c_l(k-1).
    {
        float2 cprev = cg[(unsigned)(d0 - 1 - il) & (N - 1)];
        #pragma unroll
        for (int k = 0; k < K; ++k) {
            const unsigned ul = (unsigned)(d0 + k - il);
            const unsigned uh = (unsigned)(d0 + k - ih);
            float2 cc = cg[ul & (N - 1)];
            float el = __builtin_amdgcn_exp2f(sqdist2(sp_l, cc) * (-L2E));
            float eh = __builtin_amdgcn_exp2f(sqdist2(sp_h, cprev) * (-L2E));
            k2l[k] = (ul < (unsigned)N) ? el : 0.0f;
            k2h[k] = (uh < (unsigned)N) ? eh : 0.0f;
            cprev = cc;
        }
    }

    for (int g = 0; g < NGRP; ++g) {
        const bool overlap = (d0 <= hi) && (d0 + (K - 1) >= lo);
        if (overlap) {
            if (w > 0) {
                const int p = (g ^ 1) & 1;
                int oin = ringo[w - 1][p];            // LDS broadcast
                if (!adopted) { off = oin; adopted = true; }
                if (lane == 0) {
                    int dl = off - oin;
                    int c1 = min(max(dl, -1022), 1022);
                    int c2 = min(max(dl - c1, -1022), 1022);
                    double f1 = pow2d(c1), f2 = pow2d(c2);
                    const double* q = &ringv[w - 1][p][0];
                    #pragma unroll
                    for (int k = 0; k < K; ++k)
                        vr[k] = (q[k] * f1) * f2;
                }
                #pragma unroll
                for (int k = 0; k < K; ++k) PIN_D(vr[k]);
            }

            const int kres = (ih + N - 1) - d0;  // step of hi row's last cell
            const bool pub = (lane == 63) && (w < WPB - 1);

            // Chain: two INDEPENDENT cells per step (hi uses pre-update lo).
            // f32->f64 widening of k2 is exact (bit-identical).
            #pragma unroll
            for (int k = 0; k < K; ++k) {
                double zn_h = (double)k2h[k] * ((old_lo + cur_lo) + cur_hi);
                double zn_l = (double)k2l[k] * ((nbh2 + nbh1) + cur_lo);
                if (k == kres) { res = zn_h; res_off = off; }
                if (pub) ringv[w][g & 1][k] = zn_h;   // off-chain LDS store
                old_lo = cur_lo;
                cur_lo = zn_l;
                cur_hi = zn_h;
                double a  = dpp_movd<0x111>(zn_h);   // row_shr:1
                double bc = dpp_movd<0x142>(zn_h);   // row_bcast15
                double up = ((lane & 15) == 0) ? bc : a;
                nbh2 = nbh1;
                nbh1 = (lane == 0) ? vr[k] : up;
            }

            if (pub) ringo[w][g & 1] = off;          // pre-rescale offset

            // Per-wave exact power-of-2 rescale (DPP max-reduce, no LDS).
            int el = (int)((__double_as_longlong(cur_lo) >> 52) & 0x7FF);
            int eh = (int)((__double_as_longlong(cur_hi) >> 52) & 0x7FF);
            int e = wave_max_i(max(el, eh));
            if (e > 0) {
                int sh = 1023 - e;
                int c1 = min(max(sh, -1022), 1022);
                int c2 = min(max(sh - c1, -1022), 1022);
                double f1 = pow2d(c1), f2 = pow2d(c2);
                cur_lo = (cur_lo * f1) * f2;
                cur_hi = (cur_hi * f1) * f2;
                old_lo = (old_lo * f1) * f2;
                nbh1   = (nbh1   * f1) * f2;
                nbh2   = (nbh2   * f1) * f2;
                off += sh;
            }
        }

        d0 += K;

        // Epoch bottom: next-epoch factors.
        {
            float2 cprev = cg[(unsigned)(d0 - 1 - il) & (N - 1)];
            #pragma unroll
            for (int k = 0; k < K; ++k) {
                const unsigned ul = (unsigned)(d0 + k - il);
                const unsigned uh = (unsigned)(d0 + k - ih);
                float2 cc = cg[ul & (N - 1)];
                float el2 = __builtin_amdgcn_exp2f(sqdist2(sp_l, cc) * (-L2E));
                float eh2 = __builtin_amdgcn_exp2f(sqdist2(sp_h, cprev) * (-L2E));
                k2l[k] = (ul < (unsigned)N) ? el2 : 0.0f;
                k2h[k] = (uh < (unsigned)N) ? eh2 : 0.0f;
                cprev = cc;
            }
        }
        #pragma unroll
        for (int k = 0; k < K; ++k) { PIN_F(k2l[k]); PIN_F(k2h[k]); }

        __syncthreads();
    }

    // Row 1023 = hi row of wave 7, lane 63 (t = 511): res = Z of
    // R[1023,1023] at res_off (exact snapshot; rescales are powers of 2).
    if (t == TPB - 1) {
        double R = ((double)res_off - log2(res)) * LN2D;
        atomicAdd(out, (float)(R * (1.0 / 64.0)));
    }
}

extern "C" void kernel_launch(void* const* d_in, const int* in_sizes, int n_in,
                              void* d_out, int out_size, void* d_ws, size_t ws_size,
                              hipStream_t stream) {
    const float2* snake   = (const float2*)d_in[0];
    const float2* contour = (const float2*)d_in[1];
    float* out = (float*)d_out;
    // Harness re-poisons d_out to 0xAA before every timed launch.
    hipMemsetAsync(out, 0, sizeof(float), stream);
    dtw_kernel<<<64, TPB, 0, stream>>>(snake, contour, out);
}

// Round 22
// 336.432 us; speedup vs baseline: 1.4441x; 1.0828x over previous
//
#include <hip/hip_runtime.h>

// Soft-DTW (gamma=1), batched 64 x (1024 vs 1024, 2-D points).
//
// === R22: R17/R21 champion + 2 bit-exact issue reductions ===
//  1. wave_shr:1 DPP (ctrl 0x138, gfx9-lineage whole-wave shift) replaces
//     row_shr:1 + row_bcast15 + 64-bit select in the per-step neighbor
//     exchange: lane l <- lane l-1 for l>=1, lane 0 -> 0 (bound_ctrl) then
//     selected to vr[k]. Value-for-value identical, ~4 fewer VALU ops/step.
//  2. final-cell snapshot hoisted behind a wave-uniform (w==WPB-1)
//     predicate: res is only read at t=511 (wave 7 lane 63, row 1023);
//     waves 0-6's per-step compare+cndmask chain was dead code.
// Both changes leave every computed value bit-identical -> absmax 0.0.
//
// Champion structure (R15-R17, 315.5us): one block per batch, 64 blocks x
// 512 thr, 8 waves (2 waves/SIMD), lane owns rows 2l (lo) / 2l+1 (hi); hi
// cell's predecessors are the lane's own cur_lo/old_lo (no DPP); lo+hi
// independent per step (2x ILP); contour reuse c_h(k) = c_l(k-1); LDS
// parity ring between waves; K=16 diagonals/epoch, one barrier per epoch.
// Closed axes (measured losses): cross-block CU-spread (R10/11/13/14/18),
// K=8/32 (R8/R14/R20), producer-asm pins (R19), >2 waves/SIMD.
//
// Core (verified absmax 0.0 since R8): exp2-domain Z = 2^(off - R*log2e);
//   Z_d[i] = 2^(-D*log2e) * (Zdiag + Zup + Zleft)
// Per-cell op order bit-identical: zn = k2 * ((nb2 + nb1) + cur); zero
// transcendentals on-chain; per-wave exact power-of-2 rescale per epoch
// (DPP max-reduce, pure VALU); lane-0 neighbor values converted by exact
// 2^(off-oin) two-stage factors; ring parity double-buffer (reader epoch g
// reads writer epoch g-1, parity (g^1)&1; overwrite 2 barriers later).
// Inactive cells: k2=0 -> zn=0. Final cell (row 1023, d=2046) snapshotted
// at its own step (exact); R = (res_off - log2(res)) * ln2.

#define N 1024
#define TPB 512
#define WPB 8                                  // waves per block = per batch
#define K 16                                   // diagonals per epoch
#define NGRP ((128 * (WPB - 1) + 1148) / K + (WPB - 1) + 1)   // 135
#define L2E 1.442695040888963f
#define LN2D 0.6931471805599453

#define PIN_D(x) asm volatile("" :: "v"(x))
#define PIN_F(x) asm volatile("" :: "v"(x))

__device__ __forceinline__ float sqdist2(float2 a, float2 b) {
    float dx = a.x - b.x;
    float dy = a.y - b.y;
    return dx * dx + dy * dy;
}

// 64-bit DPP move (two 32-bit halves, same lane pattern; invalid lanes -> 0).
template <int CTRL>
__device__ __forceinline__ double dpp_movd(double src) {
    long long s = __double_as_longlong(src);
    int lo = __builtin_amdgcn_update_dpp(0, (int)(s & 0xffffffffLL),
                                         CTRL, 0xF, 0xF, false);
    int hi = __builtin_amdgcn_update_dpp(0, (int)(s >> 32),
                                         CTRL, 0xF, 0xF, false);
    return __longlong_as_double(((long long)hi << 32) | (unsigned int)lo);
}

template <int CTRL>
__device__ __forceinline__ int dpp_maxstep(int x) {
    int s = __builtin_amdgcn_update_dpp(0, x, CTRL, 0xF, 0xF, false);
    return max(x, s);
}

// Full 64-lane max of a nonneg int, pure VALU (no LDS); result wave-uniform.
__device__ __forceinline__ int wave_max_i(int x) {
    x = dpp_maxstep<0x111>(x);   // row_shr:1
    x = dpp_maxstep<0x112>(x);   // row_shr:2
    x = dpp_maxstep<0x114>(x);   // row_shr:4
    x = dpp_maxstep<0x118>(x);   // row_shr:8
    x = dpp_maxstep<0x142>(x);   // row_bcast15
    x = dpp_maxstep<0x143>(x);   // row_bcast31
    return __builtin_amdgcn_readlane(x, 63);
}

// exact 2^s as double for s in [-1022, 1023]
__device__ __forceinline__ double pow2d(int s) {
    return __longlong_as_double((long long)(1023 + s) << 52);
}

__global__ __launch_bounds__(TPB, 2) void dtw_kernel(
    const float2* __restrict__ snake,
    const float2* __restrict__ contour,
    float* __restrict__ out)
{
    const int t    = threadIdx.x;
    const int lane = t & 63;
    const int w    = t >> 6;                 // wave 0..7
    const int b    = blockIdx.x;             // batch
    const int il   = (w << 7) + 2 * lane;    // lo row
    const int ih   = il + 1;                 // hi row

    __shared__ double ringv[WPB][2][K];      // boundary ring (LDS only)
    __shared__ int    ringo[WPB][2];
    __shared__ float  initvals[3];           // R0[0], R1[0], R1[1]

    const float2* sg = snake   + (size_t)b * N;
    const float2* cg = contour + (size_t)b * N;
    const float2 sp_l = sg[il];              // snake points: registers
    const float2 sp_h = sg[ih];

    if (t < WPB * 2 * K) ((double*)ringv)[t] = 0.0;   // Z(INF) = 0
    if (t < WPB * 2)     ((int*)ringo)[t] = 0;
    if (t == 0) {
        // Diagonals 0 and 1 (reference `init`):
        float2 s0 = sg[0], s1 = sg[1], c0 = cg[0], c1 = cg[1];
        float d00 = sqdist2(s0, c0);
        initvals[0] = d00;
        initvals[1] = sqdist2(s0, c1) + d00;
        initvals[2] = sqdist2(s1, c0) + d00;
    }
    __syncthreads();

    // State entering d=2 (off = 0):
    //   cur_lo = Z_{d-1}[il], cur_hi = Z_{d-1}[ih], old_lo = Z_{d-2}[il],
    //   nbh1 = Z_{d-1}[il-1], nbh2 = Z_{d-2}[il-1]  (neighbor lane's hi row)
    double cur_lo = 0.0, cur_hi = 0.0, old_lo = 0.0;
    double nbh1 = 0.0, nbh2 = 0.0;
    int off = 0;
    bool adopted = (w == 0);
    if (t == 0) {            // rows 0,1: R1[0], R1[1], R0[0]
        cur_lo = (double)__builtin_amdgcn_exp2f(-L2E * initvals[1]);
        cur_hi = (double)__builtin_amdgcn_exp2f(-L2E * initvals[2]);
        old_lo = (double)__builtin_amdgcn_exp2f(-L2E * initvals[0]);
    } else if (t == 1) {     // row 2's left neighbor = row 1 at d=1
        nbh1 = (double)__builtin_amdgcn_exp2f(-L2E * initvals[2]);
    }

    double res = 1.0;                        // final-cell snapshot
    int res_off = 0;
    const bool snapw = (w == WPB - 1);       // only row 1023's value is read

    const int lo = (w == 0) ? 2 : (128 * w - 1);  // -1 pre-step seeds nbh1
    const int hi = 128 * w + 127 + (N - 1);       // 128w + 1150
    int d0 = 2 - K * w;

    float k2l[K], k2h[K];                    // step factors, f32
    double vr[K];                            // converted ring (lane 0 only)
    #pragma unroll
    for (int k = 0; k < K; ++k) vr[k] = 0.0;

    // Epoch-0 factors. Contour reuse: c_h(k) = c_l(k-1).
    {
        float2 cprev = cg[(unsigned)(d0 - 1 - il) & (N - 1)];
        #pragma unroll
        for (int k = 0; k < K; ++k) {
            const unsigned ul = (unsigned)(d0 + k - il);
            const unsigned uh = (unsigned)(d0 + k - ih);
            float2 cc = cg[ul & (N - 1)];
            float el = __builtin_amdgcn_exp2f(sqdist2(sp_l, cc) * (-L2E));
            float eh = __builtin_amdgcn_exp2f(sqdist2(sp_h, cprev) * (-L2E));
            k2l[k] = (ul < (unsigned)N) ? el : 0.0f;
            k2h[k] = (uh < (unsigned)N) ? eh : 0.0f;
            cprev = cc;
        }
    }

    for (int g = 0; g < NGRP; ++g) {
        const bool overlap = (d0 <= hi) && (d0 + (K - 1) >= lo);
        if (overlap) {
            if (w > 0) {
                const int p = (g ^ 1) & 1;
                int oin = ringo[w - 1][p];            // LDS broadcast
                if (!adopted) { off = oin; adopted = true; }
                if (lane == 0) {
                    int dl = off - oin;
                    int c1 = min(max(dl, -1022), 1022);
                    int c2 = min(max(dl - c1, -1022), 1022);
                    double f1 = pow2d(c1), f2 = pow2d(c2);
                    const double* q = &ringv[w - 1][p][0];
                    #pragma unroll
                    for (int k = 0; k < K; ++k)
                        vr[k] = (q[k] * f1) * f2;
                }
                #pragma unroll
                for (int k = 0; k < K; ++k) PIN_D(vr[k]);
            }

            const int kres = (ih + N - 1) - d0;  // step of hi row's last cell
            const bool pub = (lane == 63) && (w < WPB - 1);

            // Chain: two INDEPENDENT cells per step (hi uses pre-update lo).
            // Neighbor pass: ONE wave_shr:1 DPP (lane l <- lane l-1; lane 0
            // bound-ctrl 0, then selected to vr[k]) -- identical values to
            // the former row_shr+bcast15+select sequence.
            #pragma unroll
            for (int k = 0; k < K; ++k) {
                double zn_h = (double)k2h[k] * ((old_lo + cur_lo) + cur_hi);
                double zn_l = (double)k2l[k] * ((nbh2 + nbh1) + cur_lo);
                if (snapw && k == kres) { res = zn_h; res_off = off; }
                if (pub) ringv[w][g & 1][k] = zn_h;   // off-chain LDS store
                old_lo = cur_lo;
                cur_lo = zn_l;
                cur_hi = zn_h;
                double up = dpp_movd<0x138>(zn_h);    // wave_shr:1
                nbh2 = nbh1;
                nbh1 = (lane == 0) ? vr[k] : up;
            }

            if (pub) ringo[w][g & 1] = off;          // pre-rescale offset

            // Per-wave exact power-of-2 rescale (DPP max-reduce, no LDS).
            int el = (int)((__double_as_longlong(cur_lo) >> 52) & 0x7FF);
            int eh = (int)((__double_as_longlong(cur_hi) >> 52) & 0x7FF);
            int e = wave_max_i(max(el, eh));
            if (e > 0) {
                int sh = 1023 - e;
                int c1 = min(max(sh, -1022), 1022);
                int c2 = min(max(sh - c1, -1022), 1022);
                double f1 = pow2d(c1), f2 = pow2d(c2);
                cur_lo = (cur_lo * f1) * f2;
                cur_hi = (cur_hi * f1) * f2;
                old_lo = (old_lo * f1) * f2;
                nbh1   = (nbh1   * f1) * f2;
                nbh2   = (nbh2   * f1) * f2;
                off += sh;
            }
        }

        d0 += K;

        // Epoch bottom: next-epoch factors.
        {
            float2 cprev = cg[(unsigned)(d0 - 1 - il) & (N - 1)];
            #pragma unroll
            for (int k = 0; k < K; ++k) {
                const unsigned ul = (unsigned)(d0 + k - il);
                const unsigned uh = (unsigned)(d0 + k - ih);
                float2 cc = cg[ul & (N - 1)];
                float el2 = __builtin_amdgcn_exp2f(sqdist2(sp_l, cc) * (-L2E));
                float eh2 = __builtin_amdgcn_exp2f(sqdist2(sp_h, cprev) * (-L2E));
                k2l[k] = (ul < (unsigned)N) ? el2 : 0.0f;
                k2h[k] = (uh < (unsigned)N) ? eh2 : 0.0f;
                cprev = cc;
            }
        }
        #pragma unroll
        for (int k = 0; k < K; ++k) { PIN_F(k2l[k]); PIN_F(k2h[k]); }

        __syncthreads();
    }

    // Row 1023 = hi row of wave 7, lane 63 (t = 511): res = Z of
    // R[1023,1023] at res_off (exact snapshot; rescales are powers of 2).
    if (t == TPB - 1) {
        double R = ((double)res_off - log2(res)) * LN2D;
        atomicAdd(out, (float)(R * (1.0 / 64.0)));
    }
}

extern "C" void kernel_launch(void* const* d_in, const int* in_sizes, int n_in,
                              void* d_out, int out_size, void* d_ws, size_t ws_size,
                              hipStream_t stream) {
    const float2* snake   = (const float2*)d_in[0];
    const float2* contour = (const float2*)d_in[1];
    float* out = (float*)d_out;
    // Harness re-poisons d_out to 0xAA before every timed launch.
    hipMemsetAsync(out, 0, sizeof(float), stream);
    dtw_kernel<<<64, TPB, 0, stream>>>(snake, contour, out);
}